// Round 1
// baseline (317.093 us; speedup 1.0000x reference)
//
#include <hip/hip_runtime.h>

#define NN 64
#define IND 256
#define NH 8
#define OD 32

__device__ __forceinline__ unsigned f2bf(float f) {
  unsigned u = __float_as_uint(f);
  return (u + (((u >> 16) & 1u) + 0x7fffu)) >> 16;  // RNE
}
__device__ __forceinline__ float bflo(unsigned u) { return __uint_as_float(u << 16); }
__device__ __forceinline__ float bfhi(unsigned u) { return __uint_as_float(u & 0xffff0000u); }

// V[h][k] = sum_d W[k, h*32+d] * Watt[h, d]   (8 x 256)
__global__ __launch_bounds__(256) void precompute_v(
    const float* __restrict__ W, const float* __restrict__ Watt, float* __restrict__ V) {
  int tid = blockIdx.x * 256 + threadIdx.x;
  if (tid >= IND * NH) return;
  int h = tid >> 8, k = tid & 255;
  float acc = 0.f;
#pragma unroll
  for (int d = 0; d < OD; ++d) acc += W[k * 256 + h * OD + d] * Watt[h * OD + d];
  V[h * 256 + k] = acc;
}

// LDS layout (bytes):
//  [0,     33792)  s as bf16 [64][264]  (row stride 264 bf16 = 132 words -> 4-bank shift/row)
//                  overlay after phase B: Yp float [4][8][256] (32768 B)
//  [33792, 42112)  v float [8][260]; overlay in epilogue: y float [8][258]
//  [42112, 44160)  e/alpha float [512]
//  [44160, 44224)  m[8], rinv[8]
#define V_OFF 33792
#define E_OFF (33792 + 8320)
#define M_OFF (33792 + 8320 + 2048)
#define SMEM_BYTES (33792 + 8320 + 2048 + 64)

__global__ __launch_bounds__(256) void gat_fused(
    const float* __restrict__ Xi, const float* __restrict__ Xj,
    const float* __restrict__ W, const float* __restrict__ V,
    float* __restrict__ out) {
  __shared__ __align__(16) unsigned char smem[SMEM_BYTES];
  unsigned* s_pk = (unsigned*)smem;             // packed bf16 pairs, word idx = (n*264+k)/2
  float* v_f = (float*)(smem + V_OFF);
  float* e_f = (float*)(smem + E_OFF);
  float* m_f = (float*)(smem + M_OFF);
  float* r_f = m_f + 8;
  float* yp_f = (float*)smem;                   // overlay (valid after phase B)
  float* y_f = (float*)(smem + V_OFF);          // overlay (valid after phase B)

  const int t = threadIdx.x;
  const int b = blockIdx.x;
  const int w = t >> 6, l = t & 63;
  const float4* Xi4 = (const float4*)Xi + (size_t)b * (NN * IND / 4);
  const float4* Xj4 = (const float4*)Xj + (size_t)b * (NN * IND / 4);

  // stage V into LDS [8][260]
#pragma unroll
  for (int r = 0; r < 8; ++r) v_f[r * 260 + t] = V[r * 256 + t];

  // Phase A: coalesced load, keep Xj in regs, s = Xi+Xj -> LDS as bf16
  float4 xj[16];
#pragma unroll
  for (int i = 0; i < 16; ++i) {
    int f4 = i * 256 + t;                       // fully coalesced float4 index
    float4 a = Xj4[f4];
    float4 c = Xi4[f4];
    xj[i] = a;
    float sx = a.x + c.x, sy = a.y + c.y, sz = a.z + c.z, sw = a.w + c.w;
    int n = i * 4 + w;                          // row; k = l*4
    unsigned p0 = f2bf(sx) | (f2bf(sy) << 16);
    unsigned p1 = f2bf(sz) | (f2bf(sw) << 16);
    *(uint2*)(s_pk + n * 132 + l * 2) = make_uint2(p0, p1);
  }
  __syncthreads();

  // Phase B: e[n][h] = leakyrelu(s[n,:] . V[h,:]); thread handles pairs p=t, t+256
#pragma unroll
  for (int pp = 0; pp < 2; ++pp) {
    int p = t + pp * 256;
    int n = p >> 3, h = p & 7;
    const uint4* srow = (const uint4*)(s_pk + n * 132);   // 8 bf16 per uint4
    const float4* vrow = (const float4*)(v_f + h * 260);
    float acc = 0.f;
#pragma unroll 8
    for (int kk = 0; kk < 32; ++kk) {
      uint4 sp = srow[kk];
      float4 va = vrow[2 * kk], vb = vrow[2 * kk + 1];
      acc += bflo(sp.x) * va.x + bfhi(sp.x) * va.y + bflo(sp.y) * va.z + bfhi(sp.y) * va.w
           + bflo(sp.z) * vb.x + bfhi(sp.z) * vb.y + bflo(sp.w) * vb.z + bfhi(sp.w) * vb.w;
    }
    e_f[p] = acc >= 0.f ? acc : 0.2f * acc;
  }
  __syncthreads();

  // softmax over n per h: wave 0 only, butterfly over 8 lane-groups
  if (t < 64) {
    int h = t & 7, g = t >> 3;
    float m = -3.4e38f;
#pragma unroll
    for (int q = 0; q < 8; ++q) m = fmaxf(m, e_f[(g * 8 + q) * 8 + h]);
    m = fmaxf(m, __shfl_xor(m, 8, 64));
    m = fmaxf(m, __shfl_xor(m, 16, 64));
    m = fmaxf(m, __shfl_xor(m, 32, 64));
    float s = 0.f;
#pragma unroll
    for (int q = 0; q < 8; ++q) s += __expf(e_f[(g * 8 + q) * 8 + h] - m);
    s += __shfl_xor(s, 8, 64);
    s += __shfl_xor(s, 16, 64);
    s += __shfl_xor(s, 32, 64);
    if (g == 0) { m_f[h] = m; r_f[h] = 1.f / s; }
  }
  __syncthreads();

  // alpha in place of e
#pragma unroll
  for (int pp = 0; pp < 2; ++pp) {
    int p = t + pp * 256;
    int h = p & 7;
    e_f[p] = __expf(e_f[p] - m_f[h]) * r_f[h];
  }
  __syncthreads();

  // Phase C: Y[h][k] partials from register-held Xj; alpha reads are wave-uniform broadcasts
  float4 acc4[8];
#pragma unroll
  for (int h = 0; h < 8; ++h) acc4[h] = make_float4(0.f, 0.f, 0.f, 0.f);
#pragma unroll
  for (int i = 0; i < 16; ++i) {
    int n = i * 4 + w;
    float4 a0 = *(const float4*)(e_f + n * 8);
    float4 a1 = *(const float4*)(e_f + n * 8 + 4);
    float al[8] = {a0.x, a0.y, a0.z, a0.w, a1.x, a1.y, a1.z, a1.w};
    float4 x = xj[i];
#pragma unroll
    for (int h = 0; h < 8; ++h) {
      acc4[h].x += al[h] * x.x;
      acc4[h].y += al[h] * x.y;
      acc4[h].z += al[h] * x.z;
      acc4[h].w += al[h] * x.w;
    }
  }
#pragma unroll
  for (int h = 0; h < 8; ++h)
    *(float4*)(yp_f + (w * 8 + h) * 256 + l * 4) = acc4[h];   // s-region overlay, safe post-B
  __syncthreads();

  // reduce the 4 wave-partials -> y[8][258]
#pragma unroll
  for (int r = 0; r < 8; ++r) {
    float y = yp_f[r * 256 + t] + yp_f[(8 + r) * 256 + t] +
              yp_f[(16 + r) * 256 + t] + yp_f[(24 + r) * 256 + t];
    y_f[r * 258 + t] = y;
  }
  __syncthreads();

  // epilogue: out[b, c=t] = elu( y[h=t/32,:] . W[:, t] ); W reads coalesced per wave
  {
    int h = t >> 5;
    const float* yrow = y_f + h * 258;
    float acc = 0.f;
#pragma unroll 8
    for (int k = 0; k < 256; ++k) acc += yrow[k] * W[k * 256 + t];
    out[(size_t)b * 256 + t] = acc > 0.f ? acc : (__expf(acc) - 1.f);
  }
}

extern "C" void kernel_launch(void* const* d_in, const int* in_sizes, int n_in,
                              void* d_out, int out_size, void* d_ws, size_t ws_size,
                              hipStream_t stream) {
  const float* Xi = (const float*)d_in[0];
  const float* Xj = (const float*)d_in[1];
  const float* W = (const float*)d_in[2];
  const float* Watt = (const float*)d_in[3];
  float* out = (float*)d_out;
  float* V = (float*)d_ws;  // 2048 floats
  int B = in_sizes[0] / (NN * IND);
  precompute_v<<<(IND * NH + 255) / 256, 256, 0, stream>>>(W, Watt, V);
  gat_fused<<<B, 256, 0, stream>>>(Xi, Xj, W, V, out);
}